// Round 6
// baseline (3554838.281 us; speedup 1.0000x reference)
//
#include <hip/hip_runtime.h>
#include <math.h>

#define B_  512
#define T_  256
#define I_  64
#define H_  512
#define G4  2048
#define K_  576   // 512 (h) + 64 (x)
#define HN  30
#define EPSf 1e-5f
#define GW  16    // blocks per group (j-blocks), bid stride 16 (same XCD under %8)
#define NG  16    // groups (m-blocks)
#define BM  32
#define BJ  32
#define KP  584   // As pitch in shorts (576 + 8 pad)
#define A1P 32    // a1p padded feature stride (128B rows -> line-disjoint groups)

typedef __attribute__((ext_vector_type(8))) short short8;
typedef __attribute__((ext_vector_type(4))) float f32x4;

static __device__ __forceinline__ unsigned short f2bf(float f) {
    unsigned int u = __float_as_uint(f);
    u += 0x7fffu + ((u >> 16) & 1u);   // round-to-nearest-even
    return (unsigned short)(u >> 16);
}
static __device__ __forceinline__ float sigf(float x) {
    return __builtin_amdgcn_rcpf(1.0f + __expf(-x));
}
static __device__ __forceinline__ float tanh_f(float x) {
    float e = __expf(-2.0f * fabsf(x));
    float r = (1.0f - e) * __builtin_amdgcn_rcpf(1.0f + e);
    return copysignf(r, x);
}
// L1-bypassing (L2-served) loads for same-XCD coherence [fast path]
static __device__ __forceinline__ short8 ld_b128_sc0(const unsigned short* p) {
    short8 v;
    asm volatile("global_load_dwordx4 %0, %1, off sc0" : "=v"(v) : "v"(p));
    return v;
}
static __device__ __forceinline__ unsigned ld_u32_sc0(const unsigned int* p) {
    unsigned v;
    asm volatile("global_load_dword %0, %1, off sc0\n\ts_waitcnt vmcnt(0)"
                 : "=v"(v) : "v"(p) : "memory");
    return v;
}

// ---------------------------------------------------------------- pack / init
__global__ void pack_kernel(const float* __restrict__ x, const float* __restrict__ Wih,
                            const float* __restrict__ Whh, const float* __restrict__ bih,
                            const float* __restrict__ bhh, const float* __restrict__ l1w,
                            unsigned short* __restrict__ Wp, unsigned short* __restrict__ xb,
                            float* __restrict__ bias, unsigned short* __restrict__ hb,
                            float* __restrict__ a1p, unsigned short* __restrict__ wl1b,
                            unsigned int* __restrict__ arr, unsigned int* __restrict__ map) {
    const int stride = gridDim.x * blockDim.x;
    const int g0 = blockIdx.x * blockDim.x + threadIdx.x;
    for (int idx = g0; idx < G4 * K_; idx += stride) {
        int n = idx / K_, k = idx - n * K_;
        float v = (k < H_) ? Whh[n * H_ + k] : Wih[n * I_ + (k - H_)];
        Wp[idx] = f2bf(v);
    }
    for (int idx = g0; idx < T_ * B_ * I_; idx += stride) {
        int t = idx / (B_ * I_);
        int r = idx - t * (B_ * I_);
        int b = r / I_, i = r - b * I_;
        xb[idx] = f2bf(x[((size_t)b * T_ + t) * I_ + i]);
    }
    for (int idx = g0; idx < G4; idx += stride) bias[idx] = bih[idx] + bhh[idx];
    for (int idx = g0; idx < B_ * H_; idx += stride) hb[idx] = 0;  // h0 = 0 (parity 0)
    for (int idx = g0; idx < T_ * B_ * A1P; idx += stride) a1p[idx] = 0.0f;
    for (int idx = g0; idx < 32 * H_; idx += stride) {
        int f = idx >> 9, k = idx & 511;
        wl1b[idx] = (f < HN) ? f2bf(l1w[f * H_ + k]) : 0;
    }
    for (int idx = g0; idx < NG * 64; idx += stride) arr[idx] = 0u;
    for (int idx = g0; idx < 256; idx += stride) map[idx] = 0u;
}

// ---------------------------------------------------------------- persistent LSTM
// 256 blocks (1/CU) x 256 threads. bid = jb*16 + mb. Group = 16 blocks, same mb
// (32 m-rows), bid stride 16 -> same XCD under round-robin dispatch (verified at
// runtime via HW_REG_XCC_ID; heterogeneous groups fall back to agent scope).
// Wave w = gate w: W slice [32j x 576k] in 144 VGPRs/lane for all 256 steps.
// Per step: stage h-tile (L2 sc0 loads) + x into LDS -> 72 MFMA/wave ->
// gate-exchange via LDS -> cell update (c in regs) -> h store (plain, L2) ->
// vmcnt drain -> L2-local counter signal -> l1 partial (1 MFMA + WG atomics).
__global__ __launch_bounds__(256, 1) void lstm_kernel(
        const unsigned short* __restrict__ Wp, const unsigned short* __restrict__ xb,
        const float* __restrict__ bias, unsigned short* __restrict__ hb,
        float* __restrict__ a1p, const unsigned short* __restrict__ wl1b,
        unsigned int* __restrict__ arr, unsigned int* __restrict__ map) {
    __shared__ unsigned short As[BM][KP];     // A-tile: h(512) | x(64), padded
    __shared__ float Gs[4][BM][33];           // gate exchange
    __shared__ unsigned short hsb[BM][40];    // new h (bf16) for l1 MFMA
    __shared__ int flagLDS;

    const int tid  = threadIdx.x;
    const int w    = tid >> 6;         // wave = gate 0..3 (i,f,g,o)
    const int lane = tid & 63;
    const int r    = lane & 15;        // MFMA: A-row / B-col / D-col
    const int q    = lane >> 4;        // MFMA: k-chunk / D-row group
    const int mb   = blockIdx.x & 15;
    const int jb   = blockIdx.x >> 4;
    const int m0   = mb * BM;
    const int j0   = jb * BJ;
    const int mloc = tid & 31;         // cell-update ownership
    const int jbase = (tid >> 5) * 4;
    const int hrow = tid >> 3, hseg = tid & 7;   // staging decomposition
    const int mt_l1 = w >> 1, ft_l1 = w & 1;     // l1 tile per wave

    if (tid == 0) {
        unsigned xcc;
        asm volatile("s_getreg_b32 %0, hwreg(HW_REG_XCC_ID)" : "=s"(xcc));
        __hip_atomic_store(&map[blockIdx.x], 0x100u | (xcc & 0xffu),
                           __ATOMIC_RELAXED, __HIP_MEMORY_SCOPE_AGENT);
    }

    // ---- persistent W fragments: gate w, 2 j-subtiles x 18 k-chunks = 144 VGPR
    short8 bfrag[2][18];
#pragma unroll
    for (int jt = 0; jt < 2; ++jt)
#pragma unroll
        for (int kc = 0; kc < 18; ++kc) {
            bfrag[jt][kc] = *reinterpret_cast<const short8*>(
                Wp + (size_t)(w * H_ + j0 + jt * 16 + r) * K_ + kc * 32 + q * 8);
            asm volatile("" : "+v"(bfrag[jt][kc]));
        }
    short8 bl1 = *reinterpret_cast<const short8*>(
        wl1b + (size_t)(ft_l1 * 16 + r) * H_ + j0 + q * 8);
    asm volatile("" : "+v"(bl1));

    float bias2[2];
#pragma unroll
    for (int jt = 0; jt < 2; ++jt) bias2[jt] = bias[w * H_ + j0 + jt * 16 + r];

    float c[4] = {0.f, 0.f, 0.f, 0.f};
    unsigned int* ctrA = arr + mb * 64;        // agent-scope counter (IF$)
    unsigned int* ctrB = arr + mb * 64 + 32;   // L2-local counter (fast mode)
    int fastf = 0;

#pragma unroll 1
    for (int t = 0; t < T_; ++t) {
        const unsigned short* hin = hb + (size_t)(t & 1) * B_ * H_;
        unsigned short* hout      = hb + (size_t)((t + 1) & 1) * B_ * H_;

        // x prefetch (plain, read-only)
        const short8 xv = *reinterpret_cast<const short8*>(
            xb + ((size_t)t * B_ + m0 + hrow) * I_ + hseg * 8);

        // ---- wait for h(t-1); bounded spins (fail loud, never wedge)
        if (t > 0) {
            if (tid == 0) {
                if (fastf) {
                    const unsigned target = (unsigned)(GW * (t - 1));
                    unsigned tries = 0;
                    while (ld_u32_sc0(ctrB) < target) {
                        if (++tries > 150000u) break;
                        __builtin_amdgcn_s_sleep(1);
                    }
                } else {
                    const unsigned target = (unsigned)(GW * t);
                    unsigned tries = 0;
                    while (__hip_atomic_load(ctrA, __ATOMIC_RELAXED,
                                             __HIP_MEMORY_SCOPE_AGENT) < target) {
                        if (++tries > 150000u) break;
                        __builtin_amdgcn_s_sleep(1);
                    }
                    if (t == 1) {   // group XCD homogeneity check
                        unsigned v0 = __hip_atomic_load(&map[mb], __ATOMIC_RELAXED,
                                                        __HIP_MEMORY_SCOPE_AGENT);
                        int same = (v0 & 0x100u) ? 1 : 0;
                        for (int u = 1; u < GW; ++u) {
                            unsigned vu = __hip_atomic_load(&map[u * 16 + mb],
                                                            __ATOMIC_RELAXED,
                                                            __HIP_MEMORY_SCOPE_AGENT);
                            same &= (vu == v0);
                        }
                        flagLDS = same;
                    }
                }
            }
            __syncthreads();
            if (t == 1) fastf = flagLDS;
            asm volatile("" ::: "memory");
        }

        // ---- stage A-tile: h rows m0..m0+31 (128B per thread) + x (16B)
        short8 hv[8];
        const unsigned short* hbase = hin + (size_t)(m0 + hrow) * H_ + hseg * 64;
        if (fastf) {
#pragma unroll
            for (int u = 0; u < 8; ++u) hv[u] = ld_b128_sc0(hbase + u * 8);
        } else {
#pragma unroll
            for (int u = 0; u < 8; ++u) {
                unsigned long long p2[2];
                p2[0] = __hip_atomic_load((const unsigned long long*)(hbase + u * 8),
                                          __ATOMIC_RELAXED, __HIP_MEMORY_SCOPE_AGENT);
                p2[1] = __hip_atomic_load((const unsigned long long*)(hbase + u * 8 + 4),
                                          __ATOMIC_RELAXED, __HIP_MEMORY_SCOPE_AGENT);
                __builtin_memcpy(&hv[u], p2, 16);
            }
        }
        asm volatile("s_waitcnt vmcnt(0)" ::: "memory");
        __builtin_amdgcn_sched_barrier(0);
        *reinterpret_cast<short8*>(&As[hrow][512 + hseg * 8]) = xv;
#pragma unroll
        for (int u = 0; u < 8; ++u)
            *reinterpret_cast<short8*>(&As[hrow][hseg * 64 + u * 8]) = hv[u];
        __syncthreads();

        // ---- GEMM: wave w computes gate w, [2 mt x 2 jt] tiles, K=576
        f32x4 acc[2][2];
#pragma unroll
        for (int mt = 0; mt < 2; ++mt)
#pragma unroll
            for (int jt = 0; jt < 2; ++jt)
                acc[mt][jt] = (f32x4){bias2[jt], bias2[jt], bias2[jt], bias2[jt]};
#pragma unroll
        for (int kc = 0; kc < 18; ++kc) {
            short8 afr[2];
#pragma unroll
            for (int mt = 0; mt < 2; ++mt)
                afr[mt] = *reinterpret_cast<const short8*>(
                    &As[mt * 16 + r][kc * 32 + q * 8]);
#pragma unroll
            for (int mt = 0; mt < 2; ++mt)
#pragma unroll
                for (int jt = 0; jt < 2; ++jt)
                    acc[mt][jt] = __builtin_amdgcn_mfma_f32_16x16x32_bf16(
                        afr[mt], bfrag[jt][kc], acc[mt][jt], 0, 0, 0);
        }

        // ---- gate exchange: D col=r, row=q*4+rr
#pragma unroll
        for (int mt = 0; mt < 2; ++mt)
#pragma unroll
            for (int jt = 0; jt < 2; ++jt)
#pragma unroll
                for (int rr = 0; rr < 4; ++rr)
                    Gs[w][mt * 16 + q * 4 + rr][jt * 16 + r] = acc[mt][jt][rr];
        __syncthreads();

        // ---- cell update: thread owns (mloc, jbase..jbase+3), c in regs
        unsigned short us[4];
#pragma unroll
        for (int rr = 0; rr < 4; ++rr) {
            const int jl = jbase + rr;
            float ig = Gs[0][mloc][jl];
            float fg = Gs[1][mloc][jl];
            float gg = Gs[2][mloc][jl];
            float og = Gs[3][mloc][jl];
            float cn = sigf(fg) * c[rr] + sigf(ig) * tanh_f(gg);
            c[rr] = cn;
            us[rr] = f2bf(sigf(og) * tanh_f(cn));
        }
        unsigned long long pv = (unsigned long long)us[0]
                              | ((unsigned long long)us[1] << 16)
                              | ((unsigned long long)us[2] << 32)
                              | ((unsigned long long)us[3] << 48);
        unsigned long long* hdst = (unsigned long long*)(hout + (size_t)(m0 + mloc) * H_
                                                         + j0 + jbase);
        if (fastf) *hdst = pv;   // plain: write-through L1 -> shared L2
        else __hip_atomic_store(hdst, pv, __ATOMIC_RELAXED, __HIP_MEMORY_SCOPE_AGENT);
        *reinterpret_cast<unsigned long long*>(&hsb[mloc][jbase]) = pv;

        // ---- release: stores at L2/IF$ before the signal
        asm volatile("s_waitcnt vmcnt(0)" ::: "memory");
        __syncthreads();
        if (tid == 0) {
            if (fastf)
                __hip_atomic_fetch_add(ctrB, 1u, __ATOMIC_RELAXED,
                                       __HIP_MEMORY_SCOPE_WORKGROUP);
            else
                __hip_atomic_fetch_add(ctrA, 1u, __ATOMIC_RELAXED,
                                       __HIP_MEMORY_SCOPE_AGENT);
        }

        // ---- l1 partial (overlaps peers' sync): 1 MFMA + 4 atomics
        const short8 ah = *reinterpret_cast<const short8*>(&hsb[mt_l1 * 16 + r][q * 8]);
        f32x4 d = __builtin_amdgcn_mfma_f32_16x16x32_bf16(
            ah, bl1, (f32x4){0.f, 0.f, 0.f, 0.f}, 0, 0, 0);
        const int f = ft_l1 * 16 + r;
        if (f < HN) {
            float* dst = a1p + ((size_t)t * B_ + m0 + mt_l1 * 16 + q * 4) * A1P + f;
#pragma unroll
            for (int rr = 0; rr < 4; ++rr) {
                if (fastf)
                    __hip_atomic_fetch_add(dst + rr * A1P, d[rr], __ATOMIC_RELAXED,
                                           __HIP_MEMORY_SCOPE_WORKGROUP);
                else
                    __hip_atomic_fetch_add(dst + rr * A1P, d[rr], __ATOMIC_RELAXED,
                                           __HIP_MEMORY_SCOPE_AGENT);
            }
        }
    }
}

// ---------------------------------------------------------------- MLP head
static __device__ __forceinline__ void bn_relu30(float v[HN], const float* __restrict__ gamma,
                                                 const float* __restrict__ beta,
                                                 float (*pS)[HN], float (*pQ)[HN]) {
    float s0[HN], s1[HN];
#pragma unroll
    for (int f = 0; f < HN; ++f) { s0[f] = v[f]; s1[f] = v[f] * v[f]; }
#pragma unroll
    for (int off = 32; off >= 1; off >>= 1) {
#pragma unroll
        for (int f = 0; f < HN; ++f) {
            s0[f] += __shfl_xor(s0[f], off);
            s1[f] += __shfl_xor(s1[f], off);
        }
    }
    const int lane = threadIdx.x & 63, w = threadIdx.x >> 6;
    if (lane == 0) {
#pragma unroll
        for (int f = 0; f < HN; ++f) { pS[w][f] = s0[f]; pQ[w][f] = s1[f]; }
    }
    __syncthreads();
#pragma unroll
    for (int f = 0; f < HN; ++f) {
        float S = 0.f, Q = 0.f;
#pragma unroll
        for (int u = 0; u < 8; ++u) { S += pS[u][f]; Q += pQ[u][f]; }
        float m = S * (1.0f / 512.0f);
        float var = Q * (1.0f / 512.0f) - m * m;     // biased, matches jnp.mean
        float inv = 1.0f / sqrtf(var + EPSf);
        float tv = gamma[f] * (v[f] - m) * inv + beta[f];
        v[f] = fmaxf(tv, 0.f);
    }
    __syncthreads();
}

static __device__ __forceinline__ void layer30(float v[HN], const float* __restrict__ w) {
    float u[HN];
#pragma unroll
    for (int f = 0; f < HN; ++f) {
        float a = 0.f;
#pragma unroll
        for (int k = 0; k < HN; ++k) a = fmaf(v[k], w[f * HN + k], a);
        u[f] = a;
    }
#pragma unroll
    for (int f = 0; f < HN; ++f) v[f] = u[f];
}

__global__ __launch_bounds__(512) void mlp_kernel(
        const float* __restrict__ a1p, const float* __restrict__ l1b,
        const float* __restrict__ l2w, const float* __restrict__ l3w,
        const float* __restrict__ l4w, const float* __restrict__ l5w,
        const float* __restrict__ gamma, const float* __restrict__ beta,
        float* __restrict__ out) {
    const int t = blockIdx.x;
    const int b = threadIdx.x;
    __shared__ float pS[8][HN], pQ[8][HN];
    float v[HN];
    const float* src = a1p + ((size_t)t * B_ + b) * A1P;
#pragma unroll
    for (int f = 0; f < HN; ++f) v[f] = src[f] + l1b[f];
    bn_relu30(v, gamma, beta, pS, pQ);
    layer30(v, l2w); bn_relu30(v, gamma, beta, pS, pQ);
    layer30(v, l3w); bn_relu30(v, gamma, beta, pS, pQ);
    layer30(v, l4w); bn_relu30(v, gamma, beta, pS, pQ);
    float o0 = 0.f, o1 = 0.f;
#pragma unroll
    for (int k = 0; k < HN; ++k) {
        o0 = fmaf(v[k], l5w[k], o0);
        o1 = fmaf(v[k], l5w[HN + k], o1);
    }
    out[(size_t)b * (2 * T_) + t]      = o0;   // out[b][0][t]
    out[(size_t)b * (2 * T_) + T_ + t] = o1;   // out[b][1][t]
}

// ---------------------------------------------------------------- launch
extern "C" void kernel_launch(void* const* d_in, const int* in_sizes, int n_in,
                              void* d_out, int out_size, void* d_ws, size_t ws_size,
                              hipStream_t stream) {
    const float* x    = (const float*)d_in[0];
    const float* Wih  = (const float*)d_in[1];
    const float* Whh  = (const float*)d_in[2];
    const float* bih  = (const float*)d_in[3];
    const float* bhh  = (const float*)d_in[4];
    const float* l1w  = (const float*)d_in[5];
    const float* l1b  = (const float*)d_in[6];
    const float* l2w  = (const float*)d_in[7];
    const float* l3w  = (const float*)d_in[8];
    const float* l4w  = (const float*)d_in[9];
    const float* l5w  = (const float*)d_in[10];
    const float* gam  = (const float*)d_in[11];
    const float* bet  = (const float*)d_in[12];
    float* out = (float*)d_out;

    char* ws = (char*)d_ws;
    unsigned short* Wp   = (unsigned short*)ws;  ws += (size_t)G4 * K_ * 2;          // 2.36 MB
    unsigned short* xb   = (unsigned short*)ws;  ws += (size_t)T_ * B_ * I_ * 2;     // 16.8 MB
    float*          bia  = (float*)ws;           ws += (size_t)G4 * 4;               // 8 KB
    unsigned short* hb   = (unsigned short*)ws;  ws += (size_t)2 * B_ * H_ * 2;      // 1 MB
    float*          a1p  = (float*)ws;           ws += (size_t)T_ * B_ * A1P * 4;    // 16.8 MB
    unsigned short* wl1b = (unsigned short*)ws;  ws += (size_t)32 * H_ * 2;          // 32 KB
    unsigned int*   arr  = (unsigned int*)ws;    ws += (size_t)NG * 64 * 4;          // 4 KB
    unsigned int*   map  = (unsigned int*)ws;    ws += (size_t)256 * 4;              // 1 KB

    pack_kernel<<<1024, 256, 0, stream>>>(x, Wih, Whh, bih, bhh, l1w,
                                          Wp, xb, bia, hb, a1p, wl1b, arr, map);
    lstm_kernel<<<NG * GW, 256, 0, stream>>>(Wp, xb, bia, hb, a1p, wl1b, arr, map);
    mlp_kernel<<<T_, 512, 0, stream>>>(a1p, l1b, l2w, l3w, l4w, l5w, gam, bet, out);
}

// Round 8
// 2070.396 us; speedup vs baseline: 1716.9850x; 1716.9850x over previous
//
#include <hip/hip_runtime.h>
#include <math.h>

#define B_  512
#define T_  256
#define I_  64
#define H_  512
#define G4  2048
#define K_  576   // 512 (h) + 64 (x)
#define HN  30
#define EPSf 1e-5f
#define GW  16    // blocks per group (j-blocks)
#define NG  16    // groups (m-blocks)
#define BM  32
#define BJ  32
#define KP  584   // As pitch in shorts (576 + 8 pad)
#define A1P 32    // a1p padded feature stride
#define HROT 4    // h buffer rotation (WAR margin)

typedef __attribute__((ext_vector_type(8))) short short8;
typedef __attribute__((ext_vector_type(4))) float f32x4;

static __device__ __forceinline__ unsigned short f2bf(float f) {
    unsigned int u = __float_as_uint(f);
    u += 0x7fffu + ((u >> 16) & 1u);   // round-to-nearest-even
    return (unsigned short)(u >> 16);
}
static __device__ __forceinline__ float sigf(float x) {
    return __builtin_amdgcn_rcpf(1.0f + __expf(-x));
}
static __device__ __forceinline__ float tanh_f(float x) {
    float e = __expf(-2.0f * fabsf(x));
    float r = (1.0f - e) * __builtin_amdgcn_rcpf(1.0f + e);
    return copysignf(r, x);
}

// ---------------------------------------------------------------- pack / init
__global__ void pack_kernel(const float* __restrict__ x, const float* __restrict__ Wih,
                            const float* __restrict__ Whh, const float* __restrict__ bih,
                            const float* __restrict__ bhh, const float* __restrict__ l1w,
                            unsigned short* __restrict__ Wp, unsigned short* __restrict__ xb,
                            float* __restrict__ bias, unsigned short* __restrict__ hb,
                            float* __restrict__ a1p, unsigned short* __restrict__ wl1b,
                            unsigned int* __restrict__ arr) {
    const int stride = gridDim.x * blockDim.x;
    const int g0 = blockIdx.x * blockDim.x + threadIdx.x;
    for (int idx = g0; idx < G4 * K_; idx += stride) {
        int n = idx / K_, k = idx - n * K_;
        float v = (k < H_) ? Whh[n * H_ + k] : Wih[n * I_ + (k - H_)];
        Wp[idx] = f2bf(v);
    }
    for (int idx = g0; idx < T_ * B_ * I_; idx += stride) {
        int t = idx / (B_ * I_);
        int r = idx - t * (B_ * I_);
        int b = r / I_, i = r - b * I_;
        xb[idx] = f2bf(x[((size_t)b * T_ + t) * I_ + i]);
    }
    for (int idx = g0; idx < G4; idx += stride) bias[idx] = bih[idx] + bhh[idx];
    for (int idx = g0; idx < B_ * H_; idx += stride) hb[idx] = 0;  // slot 0: h(-1)=0
    for (int idx = g0; idx < T_ * B_ * A1P; idx += stride) a1p[idx] = 0.0f;
    for (int idx = g0; idx < 32 * H_; idx += stride) {
        int f = idx >> 9, k = idx & 511;
        wl1b[idx] = (f < HN) ? f2bf(l1w[f * H_ + k]) : 0;
    }
    for (int idx = g0; idx < NG * 64; idx += stride) arr[idx] = 0u;
}

// ---------------------------------------------------------------- persistent LSTM
// 256 blocks (1/CU) x 256 threads. bid = jb*16 + mb. Group = 16 blocks with the
// same mb (32 m-rows); the group's h tile is produced and consumed entirely
// within the group. Coherence = R5's PROVEN mechanism only: agent-scope relaxed
// atomics for h loads, h stores, and the counter (no cache-bit assumptions, no
// XCD assumptions). Structure = R7's: W pinned in 144 VGPR/lane (wave = gate),
// A-tile staged to LDS once per block, gate exchange via LDS, c in registers,
// l1 partial off the critical path. Spins bounded: fail loud, never wedge.
__global__ __launch_bounds__(256, 1) void lstm_kernel(
        const unsigned short* __restrict__ Wp, const unsigned short* __restrict__ xb,
        const float* __restrict__ bias, unsigned short* __restrict__ hb,
        float* __restrict__ a1p, const unsigned short* __restrict__ wl1b,
        unsigned int* __restrict__ arr) {
    __shared__ unsigned short As[BM][KP];     // A-tile: h(512) | x(64), padded
    __shared__ float Gs[4][BM][33];           // gate exchange
    __shared__ unsigned short hsb[BM][40];    // new h (bf16) for l1 MFMA

    const int tid  = threadIdx.x;
    const int w    = tid >> 6;         // wave = gate 0..3 (i,f,g,o)
    const int lane = tid & 63;
    const int r    = lane & 15;        // MFMA: A-row / B-col / D-col
    const int q    = lane >> 4;        // MFMA: k-chunk / D-row group
    const int mb   = blockIdx.x & 15;
    const int jb   = blockIdx.x >> 4;
    const int m0   = mb * BM;
    const int j0   = jb * BJ;
    const int mloc = tid & 31;         // cell-update ownership
    const int jbase = (tid >> 5) * 4;
    const int hrow = tid >> 3, hseg = tid & 7;   // staging decomposition
    const int mt_l1 = w >> 1, ft_l1 = w & 1;     // l1 tile per wave

    // ---- persistent W fragments: gate w, 2 j-subtiles x 18 k-chunks = 144 VGPR
    short8 bfrag[2][18];
#pragma unroll
    for (int jt = 0; jt < 2; ++jt)
#pragma unroll
        for (int kc = 0; kc < 18; ++kc) {
            bfrag[jt][kc] = *reinterpret_cast<const short8*>(
                Wp + (size_t)(w * H_ + j0 + jt * 16 + r) * K_ + kc * 32 + q * 8);
            asm volatile("" : "+v"(bfrag[jt][kc]));
        }
    short8 bl1 = *reinterpret_cast<const short8*>(
        wl1b + (size_t)(ft_l1 * 16 + r) * H_ + j0 + q * 8);
    asm volatile("" : "+v"(bl1));

    float bias2[2];
#pragma unroll
    for (int jt = 0; jt < 2; ++jt) bias2[jt] = bias[w * H_ + j0 + jt * 16 + r];

    float c[4] = {0.f, 0.f, 0.f, 0.f};
    unsigned int* ctr = arr + mb * 64;   // one 256B-strided counter per group

#pragma unroll 1
    for (int t = 0; t < T_; ++t) {
        const unsigned short* hin = hb + (size_t)(t % HROT) * B_ * H_;
        unsigned short* hout      = hb + (size_t)((t + 1) % HROT) * B_ * H_;

        // x prefetch (plain, read-only, fresh addresses each step)
        const short8 xv = *reinterpret_cast<const short8*>(
            xb + ((size_t)t * B_ + m0 + hrow) * I_ + hseg * 8);

        // ---- wait for h(t-1): all 16 peers signaled end of step t-1
        if (t > 0) {
            if (tid == 0) {
                const unsigned target = (unsigned)(GW * t);
                unsigned tries = 0;
                while (__hip_atomic_load(ctr, __ATOMIC_RELAXED,
                                         __HIP_MEMORY_SCOPE_AGENT) < target) {
                    if (++tries > 100000u) break;   // fail loud, never wedge
                    __builtin_amdgcn_s_sleep(1);
                }
            }
            __syncthreads();
            asm volatile("" ::: "memory");
        }

        // ---- stage A-tile: h rows m0..m0+31, agent-coherent 8B loads (R5-proven)
        short8 hv[8];
        const unsigned short* hbase = hin + (size_t)(m0 + hrow) * H_ + hseg * 64;
#pragma unroll
        for (int u = 0; u < 8; ++u) {
            unsigned long long p2[2];
            p2[0] = __hip_atomic_load((const unsigned long long*)(hbase + u * 8),
                                      __ATOMIC_RELAXED, __HIP_MEMORY_SCOPE_AGENT);
            p2[1] = __hip_atomic_load((const unsigned long long*)(hbase + u * 8 + 4),
                                      __ATOMIC_RELAXED, __HIP_MEMORY_SCOPE_AGENT);
            __builtin_memcpy(&hv[u], p2, 16);
        }
        asm volatile("s_waitcnt vmcnt(0)" ::: "memory");
        __builtin_amdgcn_sched_barrier(0);
        *reinterpret_cast<short8*>(&As[hrow][512 + hseg * 8]) = xv;
#pragma unroll
        for (int u = 0; u < 8; ++u)
            *reinterpret_cast<short8*>(&As[hrow][hseg * 64 + u * 8]) = hv[u];
        __syncthreads();

        // ---- GEMM: wave w computes gate w, [2 mt x 2 jt] tiles, K=576
        f32x4 acc[2][2];
#pragma unroll
        for (int mt = 0; mt < 2; ++mt)
#pragma unroll
            for (int jt = 0; jt < 2; ++jt)
                acc[mt][jt] = (f32x4){bias2[jt], bias2[jt], bias2[jt], bias2[jt]};
#pragma unroll
        for (int kc = 0; kc < 18; ++kc) {
            short8 afr[2];
#pragma unroll
            for (int mt = 0; mt < 2; ++mt)
                afr[mt] = *reinterpret_cast<const short8*>(
                    &As[mt * 16 + r][kc * 32 + q * 8]);
#pragma unroll
            for (int mt = 0; mt < 2; ++mt)
#pragma unroll
                for (int jt = 0; jt < 2; ++jt)
                    acc[mt][jt] = __builtin_amdgcn_mfma_f32_16x16x32_bf16(
                        afr[mt], bfrag[jt][kc], acc[mt][jt], 0, 0, 0);
        }

        // ---- gate exchange: D col=r, row=q*4+rr
#pragma unroll
        for (int mt = 0; mt < 2; ++mt)
#pragma unroll
            for (int jt = 0; jt < 2; ++jt)
#pragma unroll
                for (int rr = 0; rr < 4; ++rr)
                    Gs[w][mt * 16 + q * 4 + rr][jt * 16 + r] = acc[mt][jt][rr];
        __syncthreads();

        // ---- cell update: thread owns (mloc, jbase..jbase+3), c in regs
        unsigned short us[4];
#pragma unroll
        for (int rr = 0; rr < 4; ++rr) {
            const int jl = jbase + rr;
            float ig = Gs[0][mloc][jl];
            float fg = Gs[1][mloc][jl];
            float gg = Gs[2][mloc][jl];
            float og = Gs[3][mloc][jl];
            float cn = sigf(fg) * c[rr] + sigf(ig) * tanh_f(gg);
            c[rr] = cn;
            us[rr] = f2bf(sigf(og) * tanh_f(cn));
        }
        unsigned long long pv = (unsigned long long)us[0]
                              | ((unsigned long long)us[1] << 16)
                              | ((unsigned long long)us[2] << 32)
                              | ((unsigned long long)us[3] << 48);
        // agent-coherent h store (R5-proven visibility)
        __hip_atomic_store((unsigned long long*)(hout + (size_t)(m0 + mloc) * H_
                                                 + j0 + jbase),
                           pv, __ATOMIC_RELAXED, __HIP_MEMORY_SCOPE_AGENT);
        *reinterpret_cast<unsigned long long*>(&hsb[mloc][jbase]) = pv;

        // ---- release: stores acked at coherence point before the signal
        asm volatile("s_waitcnt vmcnt(0)" ::: "memory");
        __syncthreads();
        if (tid == 0)
            __hip_atomic_fetch_add(ctr, 1u, __ATOMIC_RELAXED,
                                   __HIP_MEMORY_SCOPE_AGENT);

        // ---- l1 partial (overlaps peers' sync): 1 MFMA + 4 atomics
        const short8 ah = *reinterpret_cast<const short8*>(&hsb[mt_l1 * 16 + r][q * 8]);
        f32x4 d = __builtin_amdgcn_mfma_f32_16x16x32_bf16(
            ah, bl1, (f32x4){0.f, 0.f, 0.f, 0.f}, 0, 0, 0);
        const int f = ft_l1 * 16 + r;
        if (f < HN) {
            float* dst = a1p + ((size_t)t * B_ + m0 + mt_l1 * 16 + q * 4) * A1P + f;
#pragma unroll
            for (int rr = 0; rr < 4; ++rr)
                __hip_atomic_fetch_add(dst + rr * A1P, d[rr], __ATOMIC_RELAXED,
                                       __HIP_MEMORY_SCOPE_AGENT);
        }
    }
}

// ---------------------------------------------------------------- MLP head
static __device__ __forceinline__ void bn_relu30(float v[HN], const float* __restrict__ gamma,
                                                 const float* __restrict__ beta,
                                                 float (*pS)[HN], float (*pQ)[HN]) {
    float s0[HN], s1[HN];
#pragma unroll
    for (int f = 0; f < HN; ++f) { s0[f] = v[f]; s1[f] = v[f] * v[f]; }
#pragma unroll
    for (int off = 32; off >= 1; off >>= 1) {
#pragma unroll
        for (int f = 0; f < HN; ++f) {
            s0[f] += __shfl_xor(s0[f], off);
            s1[f] += __shfl_xor(s1[f], off);
        }
    }
    const int lane = threadIdx.x & 63, w = threadIdx.x >> 6;
    if (lane == 0) {
#pragma unroll
        for (int f = 0; f < HN; ++f) { pS[w][f] = s0[f]; pQ[w][f] = s1[f]; }
    }
    __syncthreads();
#pragma unroll
    for (int f = 0; f < HN; ++f) {
        float S = 0.f, Q = 0.f;
#pragma unroll
        for (int u = 0; u < 8; ++u) { S += pS[u][f]; Q += pQ[u][f]; }
        float m = S * (1.0f / 512.0f);
        float var = Q * (1.0f / 512.0f) - m * m;     // biased, matches jnp.mean
        float inv = 1.0f / sqrtf(var + EPSf);
        float tv = gamma[f] * (v[f] - m) * inv + beta[f];
        v[f] = fmaxf(tv, 0.f);
    }
    __syncthreads();
}

static __device__ __forceinline__ void layer30(float v[HN], const float* __restrict__ w) {
    float u[HN];
#pragma unroll
    for (int f = 0; f < HN; ++f) {
        float a = 0.f;
#pragma unroll
        for (int k = 0; k < HN; ++k) a = fmaf(v[k], w[f * HN + k], a);
        u[f] = a;
    }
#pragma unroll
    for (int f = 0; f < HN; ++f) v[f] = u[f];
}

__global__ __launch_bounds__(512) void mlp_kernel(
        const float* __restrict__ a1p, const float* __restrict__ l1b,
        const float* __restrict__ l2w, const float* __restrict__ l3w,
        const float* __restrict__ l4w, const float* __restrict__ l5w,
        const float* __restrict__ gamma, const float* __restrict__ beta,
        float* __restrict__ out) {
    const int t = blockIdx.x;
    const int b = threadIdx.x;
    __shared__ float pS[8][HN], pQ[8][HN];
    float v[HN];
    const float* src = a1p + ((size_t)t * B_ + b) * A1P;
#pragma unroll
    for (int f = 0; f < HN; ++f) v[f] = src[f] + l1b[f];
    bn_relu30(v, gamma, beta, pS, pQ);
    layer30(v, l2w); bn_relu30(v, gamma, beta, pS, pQ);
    layer30(v, l3w); bn_relu30(v, gamma, beta, pS, pQ);
    layer30(v, l4w); bn_relu30(v, gamma, beta, pS, pQ);
    float o0 = 0.f, o1 = 0.f;
#pragma unroll
    for (int k = 0; k < HN; ++k) {
        o0 = fmaf(v[k], l5w[k], o0);
        o1 = fmaf(v[k], l5w[HN + k], o1);
    }
    out[(size_t)b * (2 * T_) + t]      = o0;   // out[b][0][t]
    out[(size_t)b * (2 * T_) + T_ + t] = o1;   // out[b][1][t]
}

// ---------------------------------------------------------------- launch
extern "C" void kernel_launch(void* const* d_in, const int* in_sizes, int n_in,
                              void* d_out, int out_size, void* d_ws, size_t ws_size,
                              hipStream_t stream) {
    const float* x    = (const float*)d_in[0];
    const float* Wih  = (const float*)d_in[1];
    const float* Whh  = (const float*)d_in[2];
    const float* bih  = (const float*)d_in[3];
    const float* bhh  = (const float*)d_in[4];
    const float* l1w  = (const float*)d_in[5];
    const float* l1b  = (const float*)d_in[6];
    const float* l2w  = (const float*)d_in[7];
    const float* l3w  = (const float*)d_in[8];
    const float* l4w  = (const float*)d_in[9];
    const float* l5w  = (const float*)d_in[10];
    const float* gam  = (const float*)d_in[11];
    const float* bet  = (const float*)d_in[12];
    float* out = (float*)d_out;

    char* ws = (char*)d_ws;
    unsigned short* Wp   = (unsigned short*)ws;  ws += (size_t)G4 * K_ * 2;            // 2.36 MB
    unsigned short* xb   = (unsigned short*)ws;  ws += (size_t)T_ * B_ * I_ * 2;       // 16.8 MB
    float*          bia  = (float*)ws;           ws += (size_t)G4 * 4;                 // 8 KB
    unsigned short* hb   = (unsigned short*)ws;  ws += (size_t)HROT * B_ * H_ * 2;     // 2 MB
    float*          a1p  = (float*)ws;           ws += (size_t)T_ * B_ * A1P * 4;      // 16.8 MB
    unsigned short* wl1b = (unsigned short*)ws;  ws += (size_t)32 * H_ * 2;            // 32 KB
    unsigned int*   arr  = (unsigned int*)ws;    ws += (size_t)NG * 64 * 4;            // 4 KB

    pack_kernel<<<1024, 256, 0, stream>>>(x, Wih, Whh, bih, bhh, l1w,
                                          Wp, xb, bia, hb, a1p, wl1b, arr);
    lstm_kernel<<<NG * GW, 256, 0, stream>>>(Wp, xb, bia, hb, a1p, wl1b, arr);
    mlp_kernel<<<T_, 512, 0, stream>>>(a1p, l1b, l2w, l3w, l4w, l5w, gam, bet, out);
}

// Round 9
// 1150.833 us; speedup vs baseline: 3088.9259x; 1.7990x over previous
//
#include <hip/hip_runtime.h>
#include <math.h>

#define B_  512
#define T_  256
#define I_  64
#define H_  512
#define G4  2048
#define K_  576   // 512 (h) + 64 (x)
#define HN  30
#define EPSf 1e-5f
#define GW  16    // blocks per group (j-blocks)
#define NG  16    // groups (m-blocks)
#define BM  32
#define BJ  32
#define KP  584   // As pitch in shorts (576 + 8 pad)
#define A1P 32    // a1p padded feature stride
#define HROT 4    // h buffer rotation (WAR margin)

typedef __attribute__((ext_vector_type(8))) short short8;
typedef __attribute__((ext_vector_type(4))) float f32x4;

static __device__ __forceinline__ unsigned short f2bf(float f) {
    unsigned int u = __float_as_uint(f);
    u += 0x7fffu + ((u >> 16) & 1u);   // round-to-nearest-even
    return (unsigned short)(u >> 16);
}
static __device__ __forceinline__ float sigf(float x) {
    return __builtin_amdgcn_rcpf(1.0f + __expf(-x));
}
static __device__ __forceinline__ float tanh_f(float x) {
    float e = __expf(-2.0f * fabsf(x));
    float r = (1.0f - e) * __builtin_amdgcn_rcpf(1.0f + e);
    return copysignf(r, x);
}

// ---------------------------------------------------------------- pack / init
__global__ void pack_kernel(const float* __restrict__ x, const float* __restrict__ Wih,
                            const float* __restrict__ Whh, const float* __restrict__ bih,
                            const float* __restrict__ bhh, const float* __restrict__ l1w,
                            unsigned short* __restrict__ Wp, unsigned short* __restrict__ xb,
                            float* __restrict__ bias, unsigned short* __restrict__ hb,
                            float* __restrict__ a1p, unsigned short* __restrict__ wl1b,
                            unsigned int* __restrict__ arr) {
    const int stride = gridDim.x * blockDim.x;
    const int g0 = blockIdx.x * blockDim.x + threadIdx.x;
    for (int idx = g0; idx < G4 * K_; idx += stride) {
        int n = idx / K_, k = idx - n * K_;
        float v = (k < H_) ? Whh[n * H_ + k] : Wih[n * I_ + (k - H_)];
        Wp[idx] = f2bf(v);
    }
    for (int idx = g0; idx < T_ * B_ * I_; idx += stride) {
        int t = idx / (B_ * I_);
        int r = idx - t * (B_ * I_);
        int b = r / I_, i = r - b * I_;
        xb[idx] = f2bf(x[((size_t)b * T_ + t) * I_ + i]);
    }
    for (int idx = g0; idx < G4; idx += stride) bias[idx] = bih[idx] + bhh[idx];
    for (int idx = g0; idx < B_ * H_; idx += stride) hb[idx] = 0;  // slot 0: h(-1)=0
    for (int idx = g0; idx < T_ * B_ * A1P; idx += stride) a1p[idx] = 0.0f;
    for (int idx = g0; idx < 32 * H_; idx += stride) {
        int f = idx >> 9, k = idx & 511;
        wl1b[idx] = (f < HN) ? f2bf(l1w[f * H_ + k]) : 0;
    }
    for (int idx = g0; idx < NG * 64; idx += stride) arr[idx] = 0u;
}

// ---------------------------------------------------------------- persistent LSTM
// 256 blocks (1/CU) x 256 threads. bid = jb*16 + mb. Group = 16 blocks with the
// same mb (32 m-rows). Coherence = R5/R8-proven agent-scope relaxed atomics for
// h loads, h stores, and the counter. W pinned (lands in AGPRs, R8-verified:
// VGPR=120, no W re-fetch in FETCH_SIZE). R9 change: LDS staging is lane-
// contiguous (adjacent lanes write adjacent 16B) -- R8's 128B-strided writes
// were an 8-way bank conflict (SQ_LDS_BANK_CONFLICT 1.66e8).
__global__ __launch_bounds__(256, 1) void lstm_kernel(
        const unsigned short* __restrict__ Wp, const unsigned short* __restrict__ xb,
        const float* __restrict__ bias, unsigned short* __restrict__ hb,
        float* __restrict__ a1p, const unsigned short* __restrict__ wl1b,
        unsigned int* __restrict__ arr) {
    __shared__ unsigned short As[BM][KP];     // A-tile: h(512) | x(64), padded
    __shared__ float Gs[4][BM][33];           // gate exchange
    __shared__ unsigned short hsb[BM][40];    // new h (bf16) for l1 MFMA

    const int tid  = threadIdx.x;
    const int w    = tid >> 6;         // wave = gate 0..3 (i,f,g,o)
    const int lane = tid & 63;
    const int r    = lane & 15;        // MFMA: A-row / B-col / D-col
    const int q    = lane >> 4;        // MFMA: k-chunk / D-row group
    const int mb   = blockIdx.x & 15;
    const int jb   = blockIdx.x >> 4;
    const int m0   = mb * BM;
    const int j0   = jb * BJ;
    const int mloc = tid & 31;         // cell-update ownership
    const int jbase = (tid >> 5) * 4;
    const int hrow = tid >> 3, hseg = tid & 7;   // staging: lanes 0..7 share hrow
    const int mt_l1 = w >> 1, ft_l1 = w & 1;     // l1 tile per wave

    // ---- persistent W fragments: gate w, 2 j-subtiles x 18 k-chunks = 144 regs
    short8 bfrag[2][18];
#pragma unroll
    for (int jt = 0; jt < 2; ++jt)
#pragma unroll
        for (int kc = 0; kc < 18; ++kc) {
            bfrag[jt][kc] = *reinterpret_cast<const short8*>(
                Wp + (size_t)(w * H_ + j0 + jt * 16 + r) * K_ + kc * 32 + q * 8);
            asm volatile("" : "+v"(bfrag[jt][kc]));
        }
    short8 bl1 = *reinterpret_cast<const short8*>(
        wl1b + (size_t)(ft_l1 * 16 + r) * H_ + j0 + q * 8);
    asm volatile("" : "+v"(bl1));

    float bias2[2];
#pragma unroll
    for (int jt = 0; jt < 2; ++jt) bias2[jt] = bias[w * H_ + j0 + jt * 16 + r];

    float c[4] = {0.f, 0.f, 0.f, 0.f};
    unsigned int* ctr = arr + mb * 64;   // one 256B-strided counter per group

#pragma unroll 1
    for (int t = 0; t < T_; ++t) {
        const unsigned short* hin = hb + (size_t)(t % HROT) * B_ * H_;
        unsigned short* hout      = hb + (size_t)((t + 1) % HROT) * B_ * H_;

        // x prefetch (plain, read-only): lanes 0..7 read contiguous 128B
        const short8 xv = *reinterpret_cast<const short8*>(
            xb + ((size_t)t * B_ + m0 + hrow) * I_ + hseg * 8);

        // ---- wait for h(t-1): all 16 peers signaled end of step t-1
        if (t > 0) {
            if (tid == 0) {
                const unsigned target = (unsigned)(GW * t);
                unsigned tries = 0;
                while (__hip_atomic_load(ctr, __ATOMIC_RELAXED,
                                         __HIP_MEMORY_SCOPE_AGENT) < target) {
                    if (++tries > 100000u) break;   // fail loud, never wedge
                    __builtin_amdgcn_s_sleep(1);
                }
            }
            __syncthreads();
            asm volatile("" ::: "memory");
        }

        // ---- stage A-tile: agent-coherent 8B loads; chunk u at col u*64+hseg*8
        //      (adjacent lanes: contiguous global reads AND contiguous LDS writes)
        short8 hv[8];
        const unsigned short* hbase = hin + (size_t)(m0 + hrow) * H_ + hseg * 8;
#pragma unroll
        for (int u = 0; u < 8; ++u) {
            unsigned long long p2[2];
            p2[0] = __hip_atomic_load((const unsigned long long*)(hbase + u * 64),
                                      __ATOMIC_RELAXED, __HIP_MEMORY_SCOPE_AGENT);
            p2[1] = __hip_atomic_load((const unsigned long long*)(hbase + u * 64 + 4),
                                      __ATOMIC_RELAXED, __HIP_MEMORY_SCOPE_AGENT);
            __builtin_memcpy(&hv[u], p2, 16);
        }
        asm volatile("s_waitcnt vmcnt(0)" ::: "memory");
        __builtin_amdgcn_sched_barrier(0);
        *reinterpret_cast<short8*>(&As[hrow][512 + hseg * 8]) = xv;
#pragma unroll
        for (int u = 0; u < 8; ++u)
            *reinterpret_cast<short8*>(&As[hrow][u * 64 + hseg * 8]) = hv[u];
        __syncthreads();

        // ---- GEMM: wave w computes gate w, [2 mt x 2 jt] tiles, K=576
        f32x4 acc[2][2];
#pragma unroll
        for (int mt = 0; mt < 2; ++mt)
#pragma unroll
            for (int jt = 0; jt < 2; ++jt)
                acc[mt][jt] = (f32x4){bias2[jt], bias2[jt], bias2[jt], bias2[jt]};
#pragma unroll
        for (int kc = 0; kc < 18; ++kc) {
            short8 afr[2];
#pragma unroll
            for (int mt = 0; mt < 2; ++mt)
                afr[mt] = *reinterpret_cast<const short8*>(
                    &As[mt * 16 + r][kc * 32 + q * 8]);
#pragma unroll
            for (int mt = 0; mt < 2; ++mt)
#pragma unroll
                for (int jt = 0; jt < 2; ++jt)
                    acc[mt][jt] = __builtin_amdgcn_mfma_f32_16x16x32_bf16(
                        afr[mt], bfrag[jt][kc], acc[mt][jt], 0, 0, 0);
        }

        // ---- gate exchange: D col=r, row=q*4+rr
#pragma unroll
        for (int mt = 0; mt < 2; ++mt)
#pragma unroll
            for (int jt = 0; jt < 2; ++jt)
#pragma unroll
                for (int rr = 0; rr < 4; ++rr)
                    Gs[w][mt * 16 + q * 4 + rr][jt * 16 + r] = acc[mt][jt][rr];
        __syncthreads();

        // ---- cell update: thread owns (mloc, jbase..jbase+3), c in regs
        unsigned short us[4];
#pragma unroll
        for (int rr = 0; rr < 4; ++rr) {
            const int jl = jbase + rr;
            float ig = Gs[0][mloc][jl];
            float fg = Gs[1][mloc][jl];
            float gg = Gs[2][mloc][jl];
            float og = Gs[3][mloc][jl];
            float cn = sigf(fg) * c[rr] + sigf(ig) * tanh_f(gg);
            c[rr] = cn;
            us[rr] = f2bf(sigf(og) * tanh_f(cn));
        }
        unsigned long long pv = (unsigned long long)us[0]
                              | ((unsigned long long)us[1] << 16)
                              | ((unsigned long long)us[2] << 32)
                              | ((unsigned long long)us[3] << 48);
        // agent-coherent h store (R5-proven visibility)
        __hip_atomic_store((unsigned long long*)(hout + (size_t)(m0 + mloc) * H_
                                                 + j0 + jbase),
                           pv, __ATOMIC_RELAXED, __HIP_MEMORY_SCOPE_AGENT);
        *reinterpret_cast<unsigned long long*>(&hsb[mloc][jbase]) = pv;

        // ---- release: stores acked at coherence point before the signal
        if (t + 1 < T_) {
            asm volatile("s_waitcnt vmcnt(0)" ::: "memory");
            __syncthreads();
            if (tid == 0)
                __hip_atomic_fetch_add(ctr, 1u, __ATOMIC_RELAXED,
                                       __HIP_MEMORY_SCOPE_AGENT);
        } else {
            __syncthreads();
        }

        // ---- l1 partial (overlaps peers' sync): 1 MFMA + 4 atomics
        const short8 ah = *reinterpret_cast<const short8*>(&hsb[mt_l1 * 16 + r][q * 8]);
        f32x4 d = __builtin_amdgcn_mfma_f32_16x16x32_bf16(
            ah, bl1, (f32x4){0.f, 0.f, 0.f, 0.f}, 0, 0, 0);
        const int f = ft_l1 * 16 + r;
        if (f < HN) {
            float* dst = a1p + ((size_t)t * B_ + m0 + mt_l1 * 16 + q * 4) * A1P + f;
#pragma unroll
            for (int rr = 0; rr < 4; ++rr)
                __hip_atomic_fetch_add(dst + rr * A1P, d[rr], __ATOMIC_RELAXED,
                                       __HIP_MEMORY_SCOPE_AGENT);
        }
    }
}

// ---------------------------------------------------------------- MLP head
static __device__ __forceinline__ void bn_relu30(float v[HN], const float* __restrict__ gamma,
                                                 const float* __restrict__ beta,
                                                 float (*pS)[HN], float (*pQ)[HN]) {
    float s0[HN], s1[HN];
#pragma unroll
    for (int f = 0; f < HN; ++f) { s0[f] = v[f]; s1[f] = v[f] * v[f]; }
#pragma unroll
    for (int off = 32; off >= 1; off >>= 1) {
#pragma unroll
        for (int f = 0; f < HN; ++f) {
            s0[f] += __shfl_xor(s0[f], off);
            s1[f] += __shfl_xor(s1[f], off);
        }
    }
    const int lane = threadIdx.x & 63, w = threadIdx.x >> 6;
    if (lane == 0) {
#pragma unroll
        for (int f = 0; f < HN; ++f) { pS[w][f] = s0[f]; pQ[w][f] = s1[f]; }
    }
    __syncthreads();
#pragma unroll
    for (int f = 0; f < HN; ++f) {
        float S = 0.f, Q = 0.f;
#pragma unroll
        for (int u = 0; u < 8; ++u) { S += pS[u][f]; Q += pQ[u][f]; }
        float m = S * (1.0f / 512.0f);
        float var = Q * (1.0f / 512.0f) - m * m;     // biased, matches jnp.mean
        float inv = 1.0f / sqrtf(var + EPSf);
        float tv = gamma[f] * (v[f] - m) * inv + beta[f];
        v[f] = fmaxf(tv, 0.f);
    }
    __syncthreads();
}

static __device__ __forceinline__ void layer30(float v[HN], const float* __restrict__ w) {
    float u[HN];
#pragma unroll
    for (int f = 0; f < HN; ++f) {
        float a = 0.f;
#pragma unroll
        for (int k = 0; k < HN; ++k) a = fmaf(v[k], w[f * HN + k], a);
        u[f] = a;
    }
#pragma unroll
    for (int f = 0; f < HN; ++f) v[f] = u[f];
}

__global__ __launch_bounds__(512) void mlp_kernel(
        const float* __restrict__ a1p, const float* __restrict__ l1b,
        const float* __restrict__ l2w, const float* __restrict__ l3w,
        const float* __restrict__ l4w, const float* __restrict__ l5w,
        const float* __restrict__ gamma, const float* __restrict__ beta,
        float* __restrict__ out) {
    const int t = blockIdx.x;
    const int b = threadIdx.x;
    __shared__ float pS[8][HN], pQ[8][HN];
    float v[HN];
    const float* src = a1p + ((size_t)t * B_ + b) * A1P;
#pragma unroll
    for (int f = 0; f < HN; ++f) v[f] = src[f] + l1b[f];
    bn_relu30(v, gamma, beta, pS, pQ);
    layer30(v, l2w); bn_relu30(v, gamma, beta, pS, pQ);
    layer30(v, l3w); bn_relu30(v, gamma, beta, pS, pQ);
    layer30(v, l4w); bn_relu30(v, gamma, beta, pS, pQ);
    float o0 = 0.f, o1 = 0.f;
#pragma unroll
    for (int k = 0; k < HN; ++k) {
        o0 = fmaf(v[k], l5w[k], o0);
        o1 = fmaf(v[k], l5w[HN + k], o1);
    }
    out[(size_t)b * (2 * T_) + t]      = o0;   // out[b][0][t]
    out[(size_t)b * (2 * T_) + T_ + t] = o1;   // out[b][1][t]
}

// ---------------------------------------------------------------- launch
extern "C" void kernel_launch(void* const* d_in, const int* in_sizes, int n_in,
                              void* d_out, int out_size, void* d_ws, size_t ws_size,
                              hipStream_t stream) {
    const float* x    = (const float*)d_in[0];
    const float* Wih  = (const float*)d_in[1];
    const float* Whh  = (const float*)d_in[2];
    const float* bih  = (const float*)d_in[3];
    const float* bhh  = (const float*)d_in[4];
    const float* l1w  = (const float*)d_in[5];
    const float* l1b  = (const float*)d_in[6];
    const float* l2w  = (const float*)d_in[7];
    const float* l3w  = (const float*)d_in[8];
    const float* l4w  = (const float*)d_in[9];
    const float* l5w  = (const float*)d_in[10];
    const float* gam  = (const float*)d_in[11];
    const float* bet  = (const float*)d_in[12];
    float* out = (float*)d_out;

    char* ws = (char*)d_ws;
    unsigned short* Wp   = (unsigned short*)ws;  ws += (size_t)G4 * K_ * 2;            // 2.36 MB
    unsigned short* xb   = (unsigned short*)ws;  ws += (size_t)T_ * B_ * I_ * 2;       // 16.8 MB
    float*          bia  = (float*)ws;           ws += (size_t)G4 * 4;                 // 8 KB
    unsigned short* hb   = (unsigned short*)ws;  ws += (size_t)HROT * B_ * H_ * 2;     // 2 MB
    float*          a1p  = (float*)ws;           ws += (size_t)T_ * B_ * A1P * 4;      // 16.8 MB
    unsigned short* wl1b = (unsigned short*)ws;  ws += (size_t)32 * H_ * 2;            // 32 KB
    unsigned int*   arr  = (unsigned int*)ws;    ws += (size_t)NG * 64 * 4;            // 4 KB

    pack_kernel<<<1024, 256, 0, stream>>>(x, Wih, Whh, bih, bhh, l1w,
                                          Wp, xb, bia, hb, a1p, wl1b, arr);
    lstm_kernel<<<NG * GW, 256, 0, stream>>>(Wp, xb, bia, hb, a1p, wl1b, arr);
    mlp_kernel<<<T_, 512, 0, stream>>>(a1p, l1b, l2w, l3w, l4w, l5w, gam, bet, out);
}

// Round 10
// 981.705 us; speedup vs baseline: 3621.0847x; 1.1723x over previous
//
#include <hip/hip_runtime.h>
#include <math.h>

#define B_  512
#define T_  256
#define I_  64
#define H_  512
#define G4  2048
#define K_  576   // 512 (h) + 64 (x)
#define HN  30
#define EPSf 1e-5f
#define GW  16    // blocks per group (j-blocks)
#define NG  16    // groups (m-blocks)
#define BM  32
#define BJ  32
#define KP  584   // As pitch in shorts (576 + 8 pad)
#define A1P 32    // a1p padded feature stride
#define HROT 4    // h buffer rotation (skew<=1 + margin)

typedef __attribute__((ext_vector_type(8))) short short8;
typedef __attribute__((ext_vector_type(4))) float f32x4;

static __device__ __forceinline__ unsigned short f2bf(float f) {
    unsigned int u = __float_as_uint(f);
    u += 0x7fffu + ((u >> 16) & 1u);   // round-to-nearest-even
    return (unsigned short)(u >> 16);
}
static __device__ __forceinline__ float sigf(float x) {
    return __builtin_amdgcn_rcpf(1.0f + __expf(-x));
}
static __device__ __forceinline__ float tanh_f(float x) {
    float e = __expf(-2.0f * fabsf(x));
    float r = (1.0f - e) * __builtin_amdgcn_rcpf(1.0f + e);
    return copysignf(r, x);
}

// ---------------------------------------------------------------- pack / init
__global__ void pack_kernel(const float* __restrict__ x, const float* __restrict__ Wih,
                            const float* __restrict__ Whh, const float* __restrict__ bih,
                            const float* __restrict__ bhh, const float* __restrict__ l1w,
                            unsigned short* __restrict__ Wp, unsigned short* __restrict__ xb,
                            float* __restrict__ bias, unsigned short* __restrict__ hb,
                            float* __restrict__ a1p, unsigned short* __restrict__ wl1b,
                            unsigned int* __restrict__ arr, unsigned int* __restrict__ map) {
    const int stride = gridDim.x * blockDim.x;
    const int g0 = blockIdx.x * blockDim.x + threadIdx.x;
    for (int idx = g0; idx < G4 * K_; idx += stride) {
        int n = idx / K_, k = idx - n * K_;
        float v = (k < H_) ? Whh[n * H_ + k] : Wih[n * I_ + (k - H_)];
        Wp[idx] = f2bf(v);
    }
    for (int idx = g0; idx < T_ * B_ * I_; idx += stride) {
        int t = idx / (B_ * I_);
        int r = idx - t * (B_ * I_);
        int b = r / I_, i = r - b * I_;
        xb[idx] = f2bf(x[((size_t)b * T_ + t) * I_ + i]);
    }
    for (int idx = g0; idx < G4; idx += stride) bias[idx] = bih[idx] + bhh[idx];
    for (int idx = g0; idx < B_ * H_; idx += stride) hb[idx] = 0;  // slot 0: h(-1)=0
    for (int idx = g0; idx < T_ * B_ * A1P; idx += stride) a1p[idx] = 0.0f;
    for (int idx = g0; idx < 32 * H_; idx += stride) {
        int f = idx >> 9, k = idx & 511;
        wl1b[idx] = (f < HN) ? f2bf(l1w[f * H_ + k]) : 0;
    }
    for (int idx = g0; idx < NG * 64; idx += stride) arr[idx] = 0u;
    for (int idx = g0; idx < 256; idx += stride) map[idx] = 0u;
}

// ---------------------------------------------------------------- persistent LSTM
// 256 blocks (1/CU) x 256 threads. bid = jb*16 + mb. Group = 16 blocks, same mb.
// R10 fast path (same-XCD groups, runtime-verified): h exchange through the
// XCD's L2. Counters are atomic RMWs WITHOUT sc bits -> executed at L2 (L1 has
// no atomic units; R6/R7's failure was WORKGROUP-scope counters that never left
// the CU). h loads use global_load_dwordx4 sc0 (L1 bypass, L2-served, 16B
// coalesced -- replaces the ~2 TB/s IF$-atomic path that bound R9). h stores
// plain (write-through L1). Heterogeneous groups: R9-proven agent-atomic path.
__global__ __launch_bounds__(256, 1) void lstm_kernel(
        const unsigned short* __restrict__ Wp, const unsigned short* __restrict__ xb,
        const float* __restrict__ bias, unsigned short* __restrict__ hb,
        float* __restrict__ a1p, const unsigned short* __restrict__ wl1b,
        unsigned int* __restrict__ arr, unsigned int* __restrict__ map) {
    __shared__ unsigned short As[BM][KP];     // A-tile: h(512) | x(64), padded
    __shared__ float Gs[4][BM][33];           // gate exchange
    __shared__ unsigned short hsb[BM][40];    // new h (bf16) for l1 MFMA
    __shared__ int flagLDS;

    const int tid  = threadIdx.x;
    const int w    = tid >> 6;         // wave = gate 0..3 (i,f,g,o)
    const int lane = tid & 63;
    const int r    = lane & 15;        // MFMA: A-row / B-col / D-col
    const int q    = lane >> 4;        // MFMA: k-chunk / D-row group
    const int mb   = blockIdx.x & 15;
    const int jb   = blockIdx.x >> 4;
    const int m0   = mb * BM;
    const int j0   = jb * BJ;
    const int mloc = tid & 31;         // cell-update ownership
    const int jbase = (tid >> 5) * 4;
    const int hrow = tid >> 3, hseg = tid & 7;   // staging: lanes 0..7 share hrow
    const int mt_l1 = w >> 1, ft_l1 = w & 1;     // l1 tile per wave

    if (tid == 0) {
        unsigned xcc;
        asm volatile("s_getreg_b32 %0, hwreg(HW_REG_XCC_ID)" : "=s"(xcc));
        __hip_atomic_store(&map[blockIdx.x], 0x100u | (xcc & 0xffu),
                           __ATOMIC_RELAXED, __HIP_MEMORY_SCOPE_AGENT);
    }

    // ---- persistent W fragments: gate w, 2 j-subtiles x 18 k-chunks = 144 regs
    short8 bfrag[2][18];
#pragma unroll
    for (int jt = 0; jt < 2; ++jt)
#pragma unroll
        for (int kc = 0; kc < 18; ++kc) {
            bfrag[jt][kc] = *reinterpret_cast<const short8*>(
                Wp + (size_t)(w * H_ + j0 + jt * 16 + r) * K_ + kc * 32 + q * 8);
            asm volatile("" : "+v"(bfrag[jt][kc]));
        }
    short8 bl1 = *reinterpret_cast<const short8*>(
        wl1b + (size_t)(ft_l1 * 16 + r) * H_ + j0 + q * 8);
    asm volatile("" : "+v"(bl1));

    float bias2[2];
#pragma unroll
    for (int jt = 0; jt < 2; ++jt) bias2[jt] = bias[w * H_ + j0 + jt * 16 + r];

    float c[4] = {0.f, 0.f, 0.f, 0.f};
    unsigned int* ctrA = arr + mb * 64;        // agent-scope counter (IF$ path)
    unsigned int* ctrB = arr + mb * 64 + 32;   // L2-point counter (fast path)
    int fastf = 0;

#pragma unroll 1
    for (int t = 0; t < T_; ++t) {
        const unsigned short* hin = hb + (size_t)(t % HROT) * B_ * H_;
        unsigned short* hout      = hb + (size_t)((t + 1) % HROT) * B_ * H_;

        // x prefetch (plain, read-only): lanes 0..7 read contiguous 128B
        const short8 xv = *reinterpret_cast<const short8*>(
            xb + ((size_t)t * B_ + m0 + hrow) * I_ + hseg * 8);

        // ---- wait for h(t-1); bounded spins (fail loud, never wedge)
        if (t > 0) {
            if (tid == 0) {
                if (fastf) {
                    // L2-point RMW poll: atomics never served from L1
                    const unsigned target = (unsigned)(GW * (t - 1));
                    unsigned tries = 0;
                    for (;;) {
                        unsigned old, zero = 0;
                        asm volatile("global_atomic_add %0, %1, %2, off sc0\n\t"
                                     "s_waitcnt vmcnt(0)"
                                     : "=&v"(old) : "v"(ctrB), "v"(zero) : "memory");
                        if (old >= target) break;
                        if (++tries > 100000u) break;
                        __builtin_amdgcn_s_sleep(1);
                    }
                } else {
                    const unsigned target = (unsigned)(GW * t);
                    unsigned tries = 0;
                    while (__hip_atomic_load(ctrA, __ATOMIC_RELAXED,
                                             __HIP_MEMORY_SCOPE_AGENT) < target) {
                        if (++tries > 100000u) break;
                        __builtin_amdgcn_s_sleep(1);
                    }
                    if (t == 1) {   // group XCD homogeneity check (once)
                        unsigned v0 = __hip_atomic_load(&map[mb], __ATOMIC_RELAXED,
                                                        __HIP_MEMORY_SCOPE_AGENT);
                        int same = (v0 & 0x100u) ? 1 : 0;
                        for (int u = 1; u < GW; ++u) {
                            unsigned vu = __hip_atomic_load(&map[u * 16 + mb],
                                                            __ATOMIC_RELAXED,
                                                            __HIP_MEMORY_SCOPE_AGENT);
                            same &= (vu == v0);
                        }
                        flagLDS = same;
                    }
                }
            }
            __syncthreads();
            if (t == 1) fastf = flagLDS;
            asm volatile("" ::: "memory");
        }

        // ---- stage A-tile: 32 rows x 512 cols; chunk u at col u*64+hseg*8
        short8 hv[8];
        const unsigned short* hbase = hin + (size_t)(m0 + hrow) * H_ + hseg * 8;
        if (fastf) {
            // sc0 16B loads: bypass L1, served by the XCD's (fresh) L2
#pragma unroll
            for (int u = 0; u < 8; ++u)
                asm volatile("global_load_dwordx4 %0, %1, off sc0"
                             : "=&v"(hv[u]) : "v"(hbase + u * 64));
        } else {
#pragma unroll
            for (int u = 0; u < 8; ++u) {
                unsigned long long p2[2];
                p2[0] = __hip_atomic_load((const unsigned long long*)(hbase + u * 64),
                                          __ATOMIC_RELAXED, __HIP_MEMORY_SCOPE_AGENT);
                p2[1] = __hip_atomic_load((const unsigned long long*)(hbase + u * 64 + 4),
                                          __ATOMIC_RELAXED, __HIP_MEMORY_SCOPE_AGENT);
                __builtin_memcpy(&hv[u], p2, 16);
            }
        }
        asm volatile("s_waitcnt vmcnt(0)" ::: "memory");
        __builtin_amdgcn_sched_barrier(0);
        *reinterpret_cast<short8*>(&As[hrow][512 + hseg * 8]) = xv;
#pragma unroll
        for (int u = 0; u < 8; ++u)
            *reinterpret_cast<short8*>(&As[hrow][u * 64 + hseg * 8]) = hv[u];
        __syncthreads();

        // ---- GEMM: wave w computes gate w, [2 mt x 2 jt] tiles, K=576
        f32x4 acc[2][2];
#pragma unroll
        for (int mt = 0; mt < 2; ++mt)
#pragma unroll
            for (int jt = 0; jt < 2; ++jt)
                acc[mt][jt] = (f32x4){bias2[jt], bias2[jt], bias2[jt], bias2[jt]};
#pragma unroll
        for (int kc = 0; kc < 18; ++kc) {
            short8 afr[2];
#pragma unroll
            for (int mt = 0; mt < 2; ++mt)
                afr[mt] = *reinterpret_cast<const short8*>(
                    &As[mt * 16 + r][kc * 32 + q * 8]);
#pragma unroll
            for (int mt = 0; mt < 2; ++mt)
#pragma unroll
                for (int jt = 0; jt < 2; ++jt)
                    acc[mt][jt] = __builtin_amdgcn_mfma_f32_16x16x32_bf16(
                        afr[mt], bfrag[jt][kc], acc[mt][jt], 0, 0, 0);
        }

        // ---- gate exchange: D col=r, row=q*4+rr
#pragma unroll
        for (int mt = 0; mt < 2; ++mt)
#pragma unroll
            for (int jt = 0; jt < 2; ++jt)
#pragma unroll
                for (int rr = 0; rr < 4; ++rr)
                    Gs[w][mt * 16 + q * 4 + rr][jt * 16 + r] = acc[mt][jt][rr];
        __syncthreads();

        // ---- cell update: thread owns (mloc, jbase..jbase+3), c in regs
        unsigned short us[4];
#pragma unroll
        for (int rr = 0; rr < 4; ++rr) {
            const int jl = jbase + rr;
            float ig = Gs[0][mloc][jl];
            float fg = Gs[1][mloc][jl];
            float gg = Gs[2][mloc][jl];
            float og = Gs[3][mloc][jl];
            float cn = sigf(fg) * c[rr] + sigf(ig) * tanh_f(gg);
            c[rr] = cn;
            us[rr] = f2bf(sigf(og) * tanh_f(cn));
        }
        unsigned long long pv = (unsigned long long)us[0]
                              | ((unsigned long long)us[1] << 16)
                              | ((unsigned long long)us[2] << 32)
                              | ((unsigned long long)us[3] << 48);
        unsigned long long* hdst = (unsigned long long*)(hout + (size_t)(m0 + mloc) * H_
                                                         + j0 + jbase);
        if (fastf) *hdst = pv;   // plain store: write-through L1 -> shared L2
        else __hip_atomic_store(hdst, pv, __ATOMIC_RELAXED, __HIP_MEMORY_SCOPE_AGENT);
        *reinterpret_cast<unsigned long long*>(&hsb[mloc][jbase]) = pv;

        // ---- release: stores acked at L2/IF$ before the signal (all waves)
        if (t + 1 < T_) {
            asm volatile("s_waitcnt vmcnt(0)" ::: "memory");
            __syncthreads();
            if (tid == 0) {
                if (fastf) {
                    unsigned one = 1;
                    asm volatile("global_atomic_add %0, %1, off"
                                 :: "v"(ctrB), "v"(one) : "memory");
                } else {
                    __hip_atomic_fetch_add(ctrA, 1u, __ATOMIC_RELAXED,
                                           __HIP_MEMORY_SCOPE_AGENT);
                }
            }
        } else {
            __syncthreads();
        }

        // ---- l1 partial (overlaps peers' sync): 1 MFMA + 4 atomics
        const short8 ah = *reinterpret_cast<const short8*>(&hsb[mt_l1 * 16 + r][q * 8]);
        f32x4 d = __builtin_amdgcn_mfma_f32_16x16x32_bf16(
            ah, bl1, (f32x4){0.f, 0.f, 0.f, 0.f}, 0, 0, 0);
        const int f = ft_l1 * 16 + r;
        if (f < HN) {
            float* dst = a1p + ((size_t)t * B_ + m0 + mt_l1 * 16 + q * 4) * A1P + f;
#pragma unroll
            for (int rr = 0; rr < 4; ++rr)
                __hip_atomic_fetch_add(dst + rr * A1P, d[rr], __ATOMIC_RELAXED,
                                       __HIP_MEMORY_SCOPE_AGENT);
        }
    }
}

// ---------------------------------------------------------------- MLP head
static __device__ __forceinline__ void bn_relu30(float v[HN], const float* __restrict__ gamma,
                                                 const float* __restrict__ beta,
                                                 float (*pS)[HN], float (*pQ)[HN]) {
    float s0[HN], s1[HN];
#pragma unroll
    for (int f = 0; f < HN; ++f) { s0[f] = v[f]; s1[f] = v[f] * v[f]; }
#pragma unroll
    for (int off = 32; off >= 1; off >>= 1) {
#pragma unroll
        for (int f = 0; f < HN; ++f) {
            s0[f] += __shfl_xor(s0[f], off);
            s1[f] += __shfl_xor(s1[f], off);
        }
    }
    const int lane = threadIdx.x & 63, w = threadIdx.x >> 6;
    if (lane == 0) {
#pragma unroll
        for (int f = 0; f < HN; ++f) { pS[w][f] = s0[f]; pQ[w][f] = s1[f]; }
    }
    __syncthreads();
#pragma unroll
    for (int f = 0; f < HN; ++f) {
        float S = 0.f, Q = 0.f;
#pragma unroll
        for (int u = 0; u < 8; ++u) { S += pS[u][f]; Q += pQ[u][f]; }
        float m = S * (1.0f / 512.0f);
        float var = Q * (1.0f / 512.0f) - m * m;     // biased, matches jnp.mean
        float inv = 1.0f / sqrtf(var + EPSf);
        float tv = gamma[f] * (v[f] - m) * inv + beta[f];
        v[f] = fmaxf(tv, 0.f);
    }
    __syncthreads();
}

static __device__ __forceinline__ void layer30(float v[HN], const float* __restrict__ w) {
    float u[HN];
#pragma unroll
    for (int f = 0; f < HN; ++f) {
        float a = 0.f;
#pragma unroll
        for (int k = 0; k < HN; ++k) a = fmaf(v[k], w[f * HN + k], a);
        u[f] = a;
    }
#pragma unroll
    for (int f = 0; f < HN; ++f) v[f] = u[f];
}

__global__ __launch_bounds__(512) void mlp_kernel(
        const float* __restrict__ a1p, const float* __restrict__ l1b,
        const float* __restrict__ l2w, const float* __restrict__ l3w,
        const float* __restrict__ l4w, const float* __restrict__ l5w,
        const float* __restrict__ gamma, const float* __restrict__ beta,
        float* __restrict__ out) {
    const int t = blockIdx.x;
    const int b = threadIdx.x;
    __shared__ float pS[8][HN], pQ[8][HN];
    float v[HN];
    const float* src = a1p + ((size_t)t * B_ + b) * A1P;
#pragma unroll
    for (int f = 0; f < HN; ++f) v[f] = src[f] + l1b[f];
    bn_relu30(v, gamma, beta, pS, pQ);
    layer30(v, l2w); bn_relu30(v, gamma, beta, pS, pQ);
    layer30(v, l3w); bn_relu30(v, gamma, beta, pS, pQ);
    layer30(v, l4w); bn_relu30(v, gamma, beta, pS, pQ);
    float o0 = 0.f, o1 = 0.f;
#pragma unroll
    for (int k = 0; k < HN; ++k) {
        o0 = fmaf(v[k], l5w[k], o0);
        o1 = fmaf(v[k], l5w[HN + k], o1);
    }
    out[(size_t)b * (2 * T_) + t]      = o0;   // out[b][0][t]
    out[(size_t)b * (2 * T_) + T_ + t] = o1;   // out[b][1][t]
}

// ---------------------------------------------------------------- launch
extern "C" void kernel_launch(void* const* d_in, const int* in_sizes, int n_in,
                              void* d_out, int out_size, void* d_ws, size_t ws_size,
                              hipStream_t stream) {
    const float* x    = (const float*)d_in[0];
    const float* Wih  = (const float*)d_in[1];
    const float* Whh  = (const float*)d_in[2];
    const float* bih  = (const float*)d_in[3];
    const float* bhh  = (const float*)d_in[4];
    const float* l1w  = (const float*)d_in[5];
    const float* l1b  = (const float*)d_in[6];
    const float* l2w  = (const float*)d_in[7];
    const float* l3w  = (const float*)d_in[8];
    const float* l4w  = (const float*)d_in[9];
    const float* l5w  = (const float*)d_in[10];
    const float* gam  = (const float*)d_in[11];
    const float* bet  = (const float*)d_in[12];
    float* out = (float*)d_out;

    char* ws = (char*)d_ws;
    unsigned short* Wp   = (unsigned short*)ws;  ws += (size_t)G4 * K_ * 2;            // 2.36 MB
    unsigned short* xb   = (unsigned short*)ws;  ws += (size_t)T_ * B_ * I_ * 2;       // 16.8 MB
    float*          bia  = (float*)ws;           ws += (size_t)G4 * 4;                 // 8 KB
    unsigned short* hb   = (unsigned short*)ws;  ws += (size_t)HROT * B_ * H_ * 2;     // 2 MB
    float*          a1p  = (float*)ws;           ws += (size_t)T_ * B_ * A1P * 4;      // 16.8 MB
    unsigned short* wl1b = (unsigned short*)ws;  ws += (size_t)32 * H_ * 2;            // 32 KB
    unsigned int*   arr  = (unsigned int*)ws;    ws += (size_t)NG * 64 * 4;            // 4 KB
    unsigned int*   map  = (unsigned int*)ws;    ws += (size_t)256 * 4;                // 1 KB

    pack_kernel<<<1024, 256, 0, stream>>>(x, Wih, Whh, bih, bhh, l1w,
                                          Wp, xb, bia, hb, a1p, wl1b, arr, map);
    lstm_kernel<<<NG * GW, 256, 0, stream>>>(Wp, xb, bia, hb, a1p, wl1b, arr, map);
    mlp_kernel<<<T_, 512, 0, stream>>>(a1p, l1b, l2w, l3w, l4w, l5w, gam, bet, out);
}

// Round 11
// 952.052 us; speedup vs baseline: 3733.8698x; 1.0311x over previous
//
#include <hip/hip_runtime.h>
#include <math.h>

#define B_  512
#define T_  256
#define I_  64
#define H_  512
#define G4  2048
#define K_  576   // 512 (h) + 64 (x)
#define HN  30
#define EPSf 1e-5f
#define GW  16    // blocks per group (j-blocks)
#define NG  16    // groups (m-blocks)
#define BM  32
#define BJ  32
#define KP  584   // As pitch in shorts (576 + 8 pad)
#define A1P 32    // a1p padded feature stride
#define HROT 4    // h buffer rotation (skew<=1 + margin)

typedef __attribute__((ext_vector_type(8))) short short8;
typedef __attribute__((ext_vector_type(4))) float f32x4;

static __device__ __forceinline__ unsigned short f2bf(float f) {
    unsigned int u = __float_as_uint(f);
    u += 0x7fffu + ((u >> 16) & 1u);   // round-to-nearest-even
    return (unsigned short)(u >> 16);
}
static __device__ __forceinline__ float sigf(float x) {
    return __builtin_amdgcn_rcpf(1.0f + __expf(-x));
}
static __device__ __forceinline__ float tanh_f(float x) {
    float e = __expf(-2.0f * fabsf(x));
    float r = (1.0f - e) * __builtin_amdgcn_rcpf(1.0f + e);
    return copysignf(r, x);
}

// ---------------------------------------------------------------- pack / init
__global__ void pack_kernel(const float* __restrict__ x, const float* __restrict__ Wih,
                            const float* __restrict__ Whh, const float* __restrict__ bih,
                            const float* __restrict__ bhh, const float* __restrict__ l1w,
                            unsigned short* __restrict__ Wp, unsigned short* __restrict__ xb,
                            float* __restrict__ bias, unsigned short* __restrict__ hb,
                            float* __restrict__ a1p, unsigned short* __restrict__ wl1b,
                            unsigned int* __restrict__ arr, unsigned int* __restrict__ map) {
    const int stride = gridDim.x * blockDim.x;
    const int g0 = blockIdx.x * blockDim.x + threadIdx.x;
    for (int idx = g0; idx < G4 * K_; idx += stride) {
        int n = idx / K_, k = idx - n * K_;
        float v = (k < H_) ? Whh[n * H_ + k] : Wih[n * I_ + (k - H_)];
        Wp[idx] = f2bf(v);
    }
    for (int idx = g0; idx < T_ * B_ * I_; idx += stride) {
        int t = idx / (B_ * I_);
        int r = idx - t * (B_ * I_);
        int b = r / I_, i = r - b * I_;
        xb[idx] = f2bf(x[((size_t)b * T_ + t) * I_ + i]);
    }
    for (int idx = g0; idx < G4; idx += stride) bias[idx] = bih[idx] + bhh[idx];
    for (int idx = g0; idx < B_ * H_; idx += stride) hb[idx] = 0;  // slot 0: h(-1)=0
    for (int idx = g0; idx < T_ * B_ * A1P; idx += stride) a1p[idx] = 0.0f;
    for (int idx = g0; idx < 32 * H_; idx += stride) {
        int f = idx >> 9, k = idx & 511;
        wl1b[idx] = (f < HN) ? f2bf(l1w[f * H_ + k]) : 0;
    }
    for (int idx = g0; idx < NG * 64; idx += stride) arr[idx] = 0u;
    for (int idx = g0; idx < 256; idx += stride) map[idx] = 0u;
}

// ---------------------------------------------------------------- persistent LSTM
// 256 blocks (1/CU) x 256 threads. bid = jb*16 + mb. Group = 16 blocks, same mb.
// R11: wave = QUADRANT (mt,jt), all 4 gates per wave -- W = 4g x 18kc = 288
// regs/lane (unified-file AGPRs, R8-verified mechanism). The 4 gate values for
// each (m,j) are lane-local in acc[g] => NO Gs gate-exchange LDS (R10's
// remaining 4.8e7 bank conflicts), one fewer barrier, half the As ds_reads.
// Sync/coherence unchanged from R10 (proven): L2-point RMW counters, sc0 h
// loads, plain h stores in fast mode; agent atomics in fallback. a1p partials:
// fast mode uses L2-local plain atomics (group-exclusive 128B rows; dispatch-
// end release writes back L2 before mlp_kernel reads).
__global__ __launch_bounds__(256, 1) void lstm_kernel(
        const unsigned short* __restrict__ Wp, const unsigned short* __restrict__ xb,
        const float* __restrict__ bias, unsigned short* __restrict__ hb,
        float* __restrict__ a1p, const unsigned short* __restrict__ wl1b,
        unsigned int* __restrict__ arr, unsigned int* __restrict__ map) {
    __shared__ unsigned short As[BM][KP];     // A-tile: h(512) | x(64), padded
    __shared__ unsigned short hsb[BM][40];    // new h (bf16): store + l1 source
    __shared__ int flagLDS;

    const int tid  = threadIdx.x;
    const int w    = tid >> 6;         // wave = quadrant
    const int lane = tid & 63;
    const int r    = lane & 15;        // MFMA: A-row / B-col / D-col
    const int q    = lane >> 4;        // MFMA: k-chunk / D-row group
    const int mt   = w >> 1;           // row half (0..1)
    const int jt   = w & 1;            // col half (0..1)
    const int mb   = blockIdx.x & 15;
    const int jb   = blockIdx.x >> 4;
    const int m0   = mb * BM;
    const int j0   = jb * BJ;
    const int hrow = tid >> 3, hseg = tid & 7;   // staging: lanes 0..7 share hrow
    const int mt_l1 = w >> 1, ft_l1 = w & 1;     // l1 tile per wave

    if (tid == 0) {
        unsigned xcc;
        asm volatile("s_getreg_b32 %0, hwreg(HW_REG_XCC_ID)" : "=s"(xcc));
        __hip_atomic_store(&map[blockIdx.x], 0x100u | (xcc & 0xffu),
                           __ATOMIC_RELAXED, __HIP_MEMORY_SCOPE_AGENT);
    }

    // ---- persistent W fragments: 4 gates x 18 k-chunks for cols j0+jt*16+r
    short8 bfrag[4][18];
#pragma unroll
    for (int g = 0; g < 4; ++g)
#pragma unroll
        for (int kc = 0; kc < 18; ++kc) {
            bfrag[g][kc] = *reinterpret_cast<const short8*>(
                Wp + (size_t)(g * H_ + j0 + jt * 16 + r) * K_ + kc * 32 + q * 8);
            asm volatile("" : "+v"(bfrag[g][kc]));
        }
    short8 bl1 = *reinterpret_cast<const short8*>(
        wl1b + (size_t)(ft_l1 * 16 + r) * H_ + j0 + q * 8);
    asm volatile("" : "+v"(bl1));

    float bias_g[4];
#pragma unroll
    for (int g = 0; g < 4; ++g) bias_g[g] = bias[g * H_ + j0 + jt * 16 + r];

    float c[4] = {0.f, 0.f, 0.f, 0.f};
    unsigned int* ctrA = arr + mb * 64;        // agent-scope counter (IF$ path)
    unsigned int* ctrB = arr + mb * 64 + 32;   // L2-point counter (fast path)
    int fastf = 0;

#pragma unroll 1
    for (int t = 0; t < T_; ++t) {
        const unsigned short* hin = hb + (size_t)(t % HROT) * B_ * H_;
        unsigned short* hout      = hb + (size_t)((t + 1) % HROT) * B_ * H_;

        // x prefetch (plain, read-only): lanes 0..7 read contiguous 128B
        const short8 xv = *reinterpret_cast<const short8*>(
            xb + ((size_t)t * B_ + m0 + hrow) * I_ + hseg * 8);

        // ---- wait for h(t-1); bounded spins (fail loud, never wedge)
        if (t > 0) {
            if (tid == 0) {
                if (fastf) {
                    // L2-point RMW poll: atomics never served from L1
                    const unsigned target = (unsigned)(GW * (t - 1));
                    unsigned tries = 0;
                    for (;;) {
                        unsigned old, zero = 0;
                        asm volatile("global_atomic_add %0, %1, %2, off sc0\n\t"
                                     "s_waitcnt vmcnt(0)"
                                     : "=&v"(old) : "v"(ctrB), "v"(zero) : "memory");
                        if (old >= target) break;
                        if (++tries > 100000u) break;
                        __builtin_amdgcn_s_sleep(1);
                    }
                } else {
                    const unsigned target = (unsigned)(GW * t);
                    unsigned tries = 0;
                    while (__hip_atomic_load(ctrA, __ATOMIC_RELAXED,
                                             __HIP_MEMORY_SCOPE_AGENT) < target) {
                        if (++tries > 100000u) break;
                        __builtin_amdgcn_s_sleep(1);
                    }
                    if (t == 1) {   // group XCD homogeneity check (once)
                        unsigned v0 = __hip_atomic_load(&map[mb], __ATOMIC_RELAXED,
                                                        __HIP_MEMORY_SCOPE_AGENT);
                        int same = (v0 & 0x100u) ? 1 : 0;
                        for (int u = 1; u < GW; ++u) {
                            unsigned vu = __hip_atomic_load(&map[u * 16 + mb],
                                                            __ATOMIC_RELAXED,
                                                            __HIP_MEMORY_SCOPE_AGENT);
                            same &= (vu == v0);
                        }
                        flagLDS = same;
                    }
                }
            }
            __syncthreads();
            if (t == 1) fastf = flagLDS;
            asm volatile("" ::: "memory");
        }

        // ---- stage A-tile: 32 rows x 512 cols; chunk u at col u*64+hseg*8
        short8 hv[8];
        const unsigned short* hbase = hin + (size_t)(m0 + hrow) * H_ + hseg * 8;
        if (fastf) {
            // sc0 16B loads: bypass L1, served by the XCD's (fresh) L2
#pragma unroll
            for (int u = 0; u < 8; ++u)
                asm volatile("global_load_dwordx4 %0, %1, off sc0"
                             : "=&v"(hv[u]) : "v"(hbase + u * 64));
        } else {
#pragma unroll
            for (int u = 0; u < 8; ++u) {
                unsigned long long p2[2];
                p2[0] = __hip_atomic_load((const unsigned long long*)(hbase + u * 64),
                                          __ATOMIC_RELAXED, __HIP_MEMORY_SCOPE_AGENT);
                p2[1] = __hip_atomic_load((const unsigned long long*)(hbase + u * 64 + 4),
                                          __ATOMIC_RELAXED, __HIP_MEMORY_SCOPE_AGENT);
                __builtin_memcpy(&hv[u], p2, 16);
            }
        }
        asm volatile("s_waitcnt vmcnt(0)" ::: "memory");
        __builtin_amdgcn_sched_barrier(0);
        *reinterpret_cast<short8*>(&As[hrow][512 + hseg * 8]) = xv;
#pragma unroll
        for (int u = 0; u < 8; ++u)
            *reinterpret_cast<short8*>(&As[hrow][u * 64 + hseg * 8]) = hv[u];
        __syncthreads();

        // ---- GEMM: wave (mt,jt) computes ALL 4 gates of its 16x16 tile, K=576
        f32x4 acc[4];
#pragma unroll
        for (int g = 0; g < 4; ++g)
            acc[g] = (f32x4){bias_g[g], bias_g[g], bias_g[g], bias_g[g]};
#pragma unroll
        for (int kc = 0; kc < 18; ++kc) {
            const short8 afr = *reinterpret_cast<const short8*>(
                &As[mt * 16 + r][kc * 32 + q * 8]);
#pragma unroll
            for (int g = 0; g < 4; ++g)
                acc[g] = __builtin_amdgcn_mfma_f32_16x16x32_bf16(
                    afr, bfrag[g][kc], acc[g], 0, 0, 0);
        }

        // ---- cell update: lane-local (D col=r, row=q*4+rr); c in regs
#pragma unroll
        for (int rr = 0; rr < 4; ++rr) {
            float ig = acc[0][rr], fg = acc[1][rr], gg = acc[2][rr], og = acc[3][rr];
            float cn = sigf(fg) * c[rr] + sigf(ig) * tanh_f(gg);
            c[rr] = cn;
            hsb[mt * 16 + q * 4 + rr][jt * 16 + r] = f2bf(sigf(og) * tanh_f(cn));
        }
        __syncthreads();   // hsb complete

        // ---- h store: one 8B store per thread (row = tid>>3, 8B seg = tid&7)
        {
            unsigned long long pv;
            __builtin_memcpy(&pv, &hsb[hrow][hseg * 4], 8);
            unsigned long long* hdst = (unsigned long long*)(hout
                + (size_t)(m0 + hrow) * H_ + j0 + hseg * 4);
            if (fastf) *hdst = pv;   // plain store: write-through L1 -> shared L2
            else __hip_atomic_store(hdst, pv, __ATOMIC_RELAXED,
                                    __HIP_MEMORY_SCOPE_AGENT);
        }

        // ---- release: stores acked at L2/IF$ before the signal (all waves)
        if (t + 1 < T_) {
            asm volatile("s_waitcnt vmcnt(0)" ::: "memory");
            __syncthreads();
            if (tid == 0) {
                if (fastf) {
                    unsigned one = 1;
                    asm volatile("global_atomic_add %0, %1, off"
                                 :: "v"(ctrB), "v"(one) : "memory");
                } else {
                    __hip_atomic_fetch_add(ctrA, 1u, __ATOMIC_RELAXED,
                                           __HIP_MEMORY_SCOPE_AGENT);
                }
            }
        } else {
            __syncthreads();
        }

        // ---- l1 partial (overlaps peers' sync): 1 MFMA + 4 atomics
        const short8 ah = *reinterpret_cast<const short8*>(&hsb[mt_l1 * 16 + r][q * 8]);
        f32x4 d = __builtin_amdgcn_mfma_f32_16x16x32_bf16(
            ah, bl1, (f32x4){0.f, 0.f, 0.f, 0.f}, 0, 0, 0);
        const int f = ft_l1 * 16 + r;
        if (f < HN) {
            float* dst = a1p + ((size_t)t * B_ + m0 + mt_l1 * 16 + q * 4) * A1P + f;
            if (fastf) {
                // L2-local fire-and-forget adds (group-exclusive cache lines)
#pragma unroll
                for (int rr = 0; rr < 4; ++rr) {
                    float* p = dst + rr * A1P;
                    asm volatile("global_atomic_add_f32 %0, %1, off"
                                 :: "v"(p), "v"(d[rr]) : "memory");
                }
            } else {
#pragma unroll
                for (int rr = 0; rr < 4; ++rr)
                    __hip_atomic_fetch_add(dst + rr * A1P, d[rr], __ATOMIC_RELAXED,
                                           __HIP_MEMORY_SCOPE_AGENT);
            }
        }
    }
}

// ---------------------------------------------------------------- MLP head
static __device__ __forceinline__ void bn_relu30(float v[HN], const float* __restrict__ gamma,
                                                 const float* __restrict__ beta,
                                                 float (*pS)[HN], float (*pQ)[HN]) {
    float s0[HN], s1[HN];
#pragma unroll
    for (int f = 0; f < HN; ++f) { s0[f] = v[f]; s1[f] = v[f] * v[f]; }
#pragma unroll
    for (int off = 32; off >= 1; off >>= 1) {
#pragma unroll
        for (int f = 0; f < HN; ++f) {
            s0[f] += __shfl_xor(s0[f], off);
            s1[f] += __shfl_xor(s1[f], off);
        }
    }
    const int lane = threadIdx.x & 63, w = threadIdx.x >> 6;
    if (lane == 0) {
#pragma unroll
        for (int f = 0; f < HN; ++f) { pS[w][f] = s0[f]; pQ[w][f] = s1[f]; }
    }
    __syncthreads();
#pragma unroll
    for (int f = 0; f < HN; ++f) {
        float S = 0.f, Q = 0.f;
#pragma unroll
        for (int u = 0; u < 8; ++u) { S += pS[u][f]; Q += pQ[u][f]; }
        float m = S * (1.0f / 512.0f);
        float var = Q * (1.0f / 512.0f) - m * m;     // biased, matches jnp.mean
        float inv = 1.0f / sqrtf(var + EPSf);
        float tv = gamma[f] * (v[f] - m) * inv + beta[f];
        v[f] = fmaxf(tv, 0.f);
    }
    __syncthreads();
}

static __device__ __forceinline__ void layer30(float v[HN], const float* __restrict__ w) {
    float u[HN];
#pragma unroll
    for (int f = 0; f < HN; ++f) {
        float a = 0.f;
#pragma unroll
        for (int k = 0; k < HN; ++k) a = fmaf(v[k], w[f * HN + k], a);
        u[f] = a;
    }
#pragma unroll
    for (int f = 0; f < HN; ++f) v[f] = u[f];
}

__global__ __launch_bounds__(512) void mlp_kernel(
        const float* __restrict__ a1p, const float* __restrict__ l1b,
        const float* __restrict__ l2w, const float* __restrict__ l3w,
        const float* __restrict__ l4w, const float* __restrict__ l5w,
        const float* __restrict__ gamma, const float* __restrict__ beta,
        float* __restrict__ out) {
    const int t = blockIdx.x;
    const int b = threadIdx.x;
    __shared__ float pS[8][HN], pQ[8][HN];
    float v[HN];
    const float* src = a1p + ((size_t)t * B_ + b) * A1P;
#pragma unroll
    for (int f = 0; f < HN; ++f) v[f] = src[f] + l1b[f];
    bn_relu30(v, gamma, beta, pS, pQ);
    layer30(v, l2w); bn_relu30(v, gamma, beta, pS, pQ);
    layer30(v, l3w); bn_relu30(v, gamma, beta, pS, pQ);
    layer30(v, l4w); bn_relu30(v, gamma, beta, pS, pQ);
    float o0 = 0.f, o1 = 0.f;
#pragma unroll
    for (int k = 0; k < HN; ++k) {
        o0 = fmaf(v[k], l5w[k], o0);
        o1 = fmaf(v[k], l5w[HN + k], o1);
    }
    out[(size_t)b * (2 * T_) + t]      = o0;   // out[b][0][t]
    out[(size_t)b * (2 * T_) + T_ + t] = o1;   // out[b][1][t]
}

// ---------------------------------------------------------------- launch
extern "C" void kernel_launch(void* const* d_in, const int* in_sizes, int n_in,
                              void* d_out, int out_size, void* d_ws, size_t ws_size,
                              hipStream_t stream) {
    const float* x    = (const float*)d_in[0];
    const float* Wih  = (const float*)d_in[1];
    const float* Whh  = (const float*)d_in[2];
    const float* bih  = (const float*)d_in[3];
    const float* bhh  = (const float*)d_in[4];
    const float* l1w  = (const float*)d_in[5];
    const float* l1b  = (const float*)d_in[6];
    const float* l2w  = (const float*)d_in[7];
    const float* l3w  = (const float*)d_in[8];
    const float* l4w  = (const float*)d_in[9];
    const float* l5w  = (const float*)d_in[10];
    const float* gam  = (const float*)d_in[11];
    const float* bet  = (const float*)d_in[12];
    float* out = (float*)d_out;

    char* ws = (char*)d_ws;
    unsigned short* Wp   = (unsigned short*)ws;  ws += (size_t)G4 * K_ * 2;            // 2.36 MB
    unsigned short* xb   = (unsigned short*)ws;  ws += (size_t)T_ * B_ * I_ * 2;       // 16.8 MB
    float*          bia  = (float*)ws;           ws += (size_t)G4 * 4;                 // 8 KB
    unsigned short* hb   = (unsigned short*)ws;  ws += (size_t)HROT * B_ * H_ * 2;     // 2 MB
    float*          a1p  = (float*)ws;           ws += (size_t)T_ * B_ * A1P * 4;      // 16.8 MB
    unsigned short* wl1b = (unsigned short*)ws;  ws += (size_t)32 * H_ * 2;            // 32 KB
    unsigned int*   arr  = (unsigned int*)ws;    ws += (size_t)NG * 64 * 4;            // 4 KB
    unsigned int*   map  = (unsigned int*)ws;    ws += (size_t)256 * 4;                // 1 KB

    pack_kernel<<<1024, 256, 0, stream>>>(x, Wih, Whh, bih, bhh, l1w,
                                          Wp, xb, bia, hb, a1p, wl1b, arr, map);
    lstm_kernel<<<NG * GW, 256, 0, stream>>>(Wp, xb, bia, hb, a1p, wl1b, arr, map);
    mlp_kernel<<<T_, 512, 0, stream>>>(a1p, l1b, l2w, l3w, l4w, l5w, gam, bet, out);
}